// Round 1
// baseline (796.604 us; speedup 1.0000x reference)
//
#include <hip/hip_runtime.h>
#include <hip/hip_bf16.h>

#define E_    8
#define H_    512
#define DFF_  2048
#define T_    8192
#define MT    32     // token rows per FFN block
#define BD    32     // DFF chunk

typedef float  f32x4  __attribute__((ext_vector_type(4)));
typedef short  bf16x8 __attribute__((ext_vector_type(8)));

static __device__ __forceinline__ ushort f2bf(float f) {
  union { float f; unsigned u; } v; v.f = f;
  unsigned r = v.u + 0x7FFFu + ((v.u >> 16) & 1u);
  return (ushort)(r >> 16);
}

// ---------------- router: fp32 logits, top-2, softmax, scatter to expert lists
__global__ void router_kernel(const float* __restrict__ x, const float* __restrict__ gw,
                              int* __restrict__ counts, int* __restrict__ ltok,
                              float* __restrict__ lw) {
  int wave = (blockIdx.x * blockDim.x + threadIdx.x) >> 6;
  int lane = threadIdx.x & 63;
  if (wave >= T_) return;
  const float4* xr = (const float4*)(x + (size_t)wave * H_ + lane * 8);
  float4 x0 = xr[0], x1 = xr[1];
  float acc[E_];
#pragma unroll
  for (int e = 0; e < E_; ++e) {
    const float4* gr = (const float4*)(gw + e * H_ + lane * 8);
    float4 g0 = gr[0], g1 = gr[1];
    acc[e] = x0.x*g0.x + x0.y*g0.y + x0.z*g0.z + x0.w*g0.w
           + x1.x*g1.x + x1.y*g1.y + x1.z*g1.z + x1.w*g1.w;
  }
#pragma unroll
  for (int e = 0; e < E_; ++e) {
#pragma unroll
    for (int off = 32; off; off >>= 1)
      acc[e] += __shfl_xor(acc[e], off);
  }
  if (lane == 0) {
    float v1 = -1e30f, v2 = -1e30f; int i1 = 0, i2 = 0;
#pragma unroll
    for (int e = 0; e < E_; ++e) {
      float v = acc[e];
      if (v > v1)      { v2 = v1; i2 = i1; v1 = v; i1 = e; }
      else if (v > v2) { v2 = v;  i2 = e; }
    }
    float ex = expf(v2 - v1);
    float inv = 1.0f / (1.0f + ex);
    float wa = inv, wb = ex * inv;
    int p1 = atomicAdd(&counts[i1], 1);
    ltok[i1 * T_ + p1] = wave;  lw[i1 * T_ + p1] = wa;
    int p2 = atomicAdd(&counts[i2], 1);
    ltok[i2 * T_ + p2] = wave;  lw[i2 * T_ + p2] = wb;
  }
}

// ---------------- transpose + fp32->bf16 cast: in (E,R,C) f32 -> out (E,C,R) bf16
__global__ void transpose_cast_kernel(const float* __restrict__ in,
                                      ushort* __restrict__ out, int R, int C) {
  int e = blockIdx.z, r0 = blockIdx.y * 64, c0 = blockIdx.x * 64;
  __shared__ float tile[64][65];
  int t = threadIdx.x;
  int row = t >> 2, seg = t & 3;
  const float* src = in + ((size_t)e * R + r0 + row) * C + c0 + seg * 16;
#pragma unroll
  for (int i = 0; i < 4; ++i) {
    float4 v = *(const float4*)(src + i * 4);
    tile[row][seg * 16 + i * 4 + 0] = v.x;
    tile[row][seg * 16 + i * 4 + 1] = v.y;
    tile[row][seg * 16 + i * 4 + 2] = v.z;
    tile[row][seg * 16 + i * 4 + 3] = v.w;
  }
  __syncthreads();
  int c = t >> 2;
  ushort vals[16];
#pragma unroll
  for (int j = 0; j < 16; ++j) vals[j] = f2bf(tile[seg * 16 + j][c]);
  ushort* dst = out + ((size_t)e * C + c0 + c) * R + r0 + seg * 16;
  *(uint4*)(dst)     = *(uint4*)&vals[0];
  *(uint4*)(dst + 8) = *(uint4*)&vals[8];
}

// ---------------- fused expert FFN: (gather 32 tokens) @ w1 -> gelu -> @ w2 -> scatter-add
__global__ __launch_bounds__(256, 2) void ffn_kernel(
    const float* __restrict__ x, const float* __restrict__ b1, const float* __restrict__ b2,
    const int* __restrict__ counts, const int* __restrict__ ltok, const float* __restrict__ lw,
    const ushort* __restrict__ w1t, const ushort* __restrict__ w2t,
    float* __restrict__ out) {
  int e = blockIdx.x & (E_ - 1);
  int tile = blockIdx.x >> 3;
  int cnt = counts[e];
  int m0 = tile * MT;
  if (m0 >= cnt) return;

  int tid = threadIdx.x;
  int lane = tid & 63;
  int w = tid >> 6;
  int mf1 = w >> 1, nf1 = w & 1;   // GEMM1: wave's 16x16 tile of the 32x32 hdn chunk
  int nbase = w * 128;             // GEMM2: wave's 128-wide out slice

  __shared__ ushort sW1[BD][H_ + 8];   // [d_local][h]   (w1 transposed)
  __shared__ ushort sW2[H_][BD + 8];   // [n][d_local]   (w2 transposed)
  __shared__ ushort sH[MT][BD + 8];    // [m][d_local]   gelu(hdn) chunk, bf16

  // X A-fragments in registers: 16 K-steps of 16x32
  int rr = m0 + mf1 * 16 + (lane & 15);
  if (rr > cnt - 1) rr = cnt - 1;
  int tok = ltok[e * T_ + rr];
  const float* xrow = x + (size_t)tok * H_ + ((lane >> 4) * 8);
  bf16x8 afrag[16];
#pragma unroll
  for (int ks = 0; ks < 16; ++ks) {
    float4 f0 = *(const float4*)(xrow + ks * 32);
    float4 f1 = *(const float4*)(xrow + ks * 32 + 4);
    bf16x8 a;
    a[0] = f2bf(f0.x); a[1] = f2bf(f0.y); a[2] = f2bf(f0.z); a[3] = f2bf(f0.w);
    a[4] = f2bf(f1.x); a[5] = f2bf(f1.y); a[6] = f2bf(f1.z); a[7] = f2bf(f1.w);
    afrag[ks] = a;
  }

  f32x4 acc2[2][8];
#pragma unroll
  for (int i = 0; i < 2; ++i)
#pragma unroll
    for (int j = 0; j < 8; ++j) acc2[i][j] = (f32x4){0.f, 0.f, 0.f, 0.f};

  const ushort* w1e = w1t + (size_t)e * DFF_ * H_;
  const ushort* w2e = w2t + (size_t)e * H_ * DFF_;

  for (int c = 0; c < DFF_ / BD; ++c) {
    int d0 = c * BD;
    __syncthreads();   // protect sW1/sW2 from previous chunk's readers
    {  // stage w1t rows d0..d0+31 (each 512 bf16)
      int d = tid >> 3, seg = tid & 7;
      const uint4* src = (const uint4*)(w1e + (size_t)(d0 + d) * H_ + seg * 64);
      uint4* dst = (uint4*)(&sW1[d][seg * 64]);
#pragma unroll
      for (int i = 0; i < 8; ++i) dst[i] = src[i];
    }
    {  // stage w2t[:, d0..d0+31] (512 rows x 32 bf16)
#pragma unroll
      for (int h = 0; h < 2; ++h) {
        int n = tid + h * 256;
        const uint4* src = (const uint4*)(w2e + (size_t)n * DFF_ + d0);
        uint4* dst = (uint4*)(&sW2[n][0]);
#pragma unroll
        for (int i = 0; i < 4; ++i) dst[i] = src[i];
      }
    }
    __syncthreads();

    // GEMM1: hdn(32x32) = X(32x512) @ w1[:,d0:d0+32]; one 16x16 tile per wave
    f32x4 acc1 = {0.f, 0.f, 0.f, 0.f};
#pragma unroll
    for (int ks = 0; ks < 16; ++ks) {
      bf16x8 b = *(const bf16x8*)(&sW1[nf1 * 16 + (lane & 15)][ks * 32 + (lane >> 4) * 8]);
      acc1 = __builtin_amdgcn_mfma_f32_16x16x32_bf16(afrag[ks], b, acc1, 0, 0, 0);
    }
    // bias + tanh-approx gelu -> bf16 -> LDS
    int dcol = nf1 * 16 + (lane & 15);
    float b1v = b1[e * DFF_ + d0 + dcol];
#pragma unroll
    for (int j = 0; j < 4; ++j) {
      float v = acc1[j] + b1v;
      float th = tanhf(0.7978845608028654f * (v + 0.044715f * v * v * v));
      float g = 0.5f * v * (1.0f + th);
      sH[mf1 * 16 + (lane >> 4) * 4 + j][dcol] = f2bf(g);
    }
    __syncthreads();

    // GEMM2: out(32x512) += hdn(32x32) @ w2[d0:d0+32, :]; wave owns 32x128 slice
#pragma unroll
    for (int mf = 0; mf < 2; ++mf) {
      bf16x8 a = *(const bf16x8*)(&sH[mf * 16 + (lane & 15)][(lane >> 4) * 8]);
#pragma unroll
      for (int nf = 0; nf < 8; ++nf) {
        bf16x8 b = *(const bf16x8*)(&sW2[nbase + nf * 16 + (lane & 15)][(lane >> 4) * 8]);
        acc2[mf][nf] = __builtin_amdgcn_mfma_f32_16x16x32_bf16(a, b, acc2[mf][nf], 0, 0, 0);
      }
    }
  }

  // epilogue: weighted scatter-add (token may belong to 2 experts -> atomic)
#pragma unroll
  for (int mf = 0; mf < 2; ++mf) {
#pragma unroll
    for (int j = 0; j < 4; ++j) {
      int gr = m0 + mf * 16 + (lane >> 4) * 4 + j;
      if (gr < cnt) {
        int tok2 = ltok[e * T_ + gr];
        float wgt = lw[e * T_ + gr];
#pragma unroll
        for (int nf = 0; nf < 8; ++nf) {
          int col = nbase + nf * 16 + (lane & 15);
          float v = wgt * (acc2[mf][nf][j] + b2[e * H_ + col]);
          atomicAdd(&out[(size_t)tok2 * H_ + col], v);
        }
      }
    }
  }
}

extern "C" void kernel_launch(void* const* d_in, const int* in_sizes, int n_in,
                              void* d_out, int out_size, void* d_ws, size_t ws_size,
                              hipStream_t stream) {
  const float* x  = (const float*)d_in[0];
  const float* gw = (const float*)d_in[1];
  const float* w1 = (const float*)d_in[2];
  const float* b1 = (const float*)d_in[3];
  const float* w2 = (const float*)d_in[4];
  const float* b2 = (const float*)d_in[5];
  float* out = (float*)d_out;

  char* ws = (char*)d_ws;
  int*    counts = (int*)ws;                                   // 256 B
  int*    ltok   = (int*)(ws + 256);                           // E*T*4
  float*  lw     = (float*)(ws + 256 + (size_t)E_ * T_ * 4);   // E*T*4
  ushort* w1t    = (ushort*)(ws + 256 + 2 * (size_t)E_ * T_ * 4);
  ushort* w2t    = (ushort*)((char*)w1t + (size_t)E_ * DFF_ * H_ * 2);

  hipMemsetAsync(counts, 0, 256, stream);
  hipMemsetAsync(out, 0, (size_t)out_size * sizeof(float), stream);

  router_kernel<<<T_ / 4, 256, 0, stream>>>(x, gw, counts, ltok, lw);
  transpose_cast_kernel<<<dim3(DFF_ / 64, H_ / 64, E_), 256, 0, stream>>>(w1, w1t, H_, DFF_);
  transpose_cast_kernel<<<dim3(H_ / 64, DFF_ / 64, E_), 256, 0, stream>>>(w2, w2t, DFF_, H_);
  ffn_kernel<<<(T_ / MT) * E_, 256, 0, stream>>>(x, b1, b2, counts, ltok, lw, w1t, w2t, out);
}

// Round 2
// 362.805 us; speedup vs baseline: 2.1957x; 2.1957x over previous
//
#include <hip/hip_runtime.h>
#include <hip/hip_bf16.h>

#define E_    8
#define H_    512
#define DFF_  2048
#define T_    8192
#define NSLOT (2 * T_)

typedef float  f32x4  __attribute__((ext_vector_type(4)));
typedef short  bf16x8 __attribute__((ext_vector_type(8)));

static __device__ __forceinline__ ushort f2bf(float f) {
  union { float f; unsigned u; } v; v.f = f;
  unsigned r = v.u + 0x7FFFu + ((v.u >> 16) & 1u);
  return (ushort)(r >> 16);
}

// async global->LDS, 16B per lane; LDS dest is wave-uniform base + lane*16
static __device__ __forceinline__ void gload16(const void* g, void* l) {
  __builtin_amdgcn_global_load_lds((const __attribute__((address_space(1))) void*)g,
                                   (__attribute__((address_space(3))) void*)l, 16, 0, 0);
}

// ---------------- cast X fp32 -> bf16 (row layout preserved)
__global__ void cast_x_kernel(const float* __restrict__ x, ushort* __restrict__ xb) {
  size_t i = (size_t)blockIdx.x * 256 + threadIdx.x;  // 8 elements per thread
  const float4* s = (const float4*)(x + i * 8);
  float4 a = s[0], b = s[1];
  ushort v[8] = {f2bf(a.x), f2bf(a.y), f2bf(a.z), f2bf(a.w),
                 f2bf(b.x), f2bf(b.y), f2bf(b.z), f2bf(b.w)};
  *(uint4*)(xb + i * 8) = *(uint4*)v;
}

// ---------------- router: fp32 logits, top-2, softmax, build per-expert slot lists
__global__ void router_kernel(const float* __restrict__ x, const float* __restrict__ gw,
                              int* __restrict__ counts, int* __restrict__ lslot,
                              float* __restrict__ slotw, int* __restrict__ slote) {
  int wave = (blockIdx.x * blockDim.x + threadIdx.x) >> 6;
  int lane = threadIdx.x & 63;
  if (wave >= T_) return;
  const float4* xr = (const float4*)(x + (size_t)wave * H_ + lane * 8);
  float4 x0 = xr[0], x1 = xr[1];
  float acc[E_];
#pragma unroll
  for (int e = 0; e < E_; ++e) {
    const float4* gr = (const float4*)(gw + e * H_ + lane * 8);
    float4 g0 = gr[0], g1 = gr[1];
    acc[e] = x0.x*g0.x + x0.y*g0.y + x0.z*g0.z + x0.w*g0.w
           + x1.x*g1.x + x1.y*g1.y + x1.z*g1.z + x1.w*g1.w;
  }
#pragma unroll
  for (int e = 0; e < E_; ++e) {
#pragma unroll
    for (int off = 32; off; off >>= 1)
      acc[e] += __shfl_xor(acc[e], off);
  }
  if (lane == 0) {
    float v1 = -1e30f, v2 = -1e30f; int i1 = 0, i2 = 0;
#pragma unroll
    for (int e = 0; e < E_; ++e) {
      float v = acc[e];
      if (v > v1)      { v2 = v1; i2 = i1; v1 = v; i1 = e; }
      else if (v > v2) { v2 = v;  i2 = e; }
    }
    float ex = expf(v2 - v1);
    float inv = 1.0f / (1.0f + ex);
    float wa = inv, wb = ex * inv;
    int p1 = atomicAdd(&counts[i1], 1);
    lslot[i1 * T_ + p1] = 2 * wave;
    slotw[2 * wave] = wa; slote[2 * wave] = i1;
    int p2 = atomicAdd(&counts[i2], 1);
    lslot[i2 * T_ + p2] = 2 * wave + 1;
    slotw[2 * wave + 1] = wb; slote[2 * wave + 1] = i2;
  }
}

// ---------------- transpose + fp32->bf16 cast: in (E,R,C) f32 -> out (E,C,R) bf16
__global__ void transpose_cast_kernel(const float* __restrict__ in,
                                      ushort* __restrict__ out, int R, int C) {
  int e = blockIdx.z, r0 = blockIdx.y * 64, c0 = blockIdx.x * 64;
  __shared__ float tile[64][65];
  int t = threadIdx.x;
  int row = t >> 2, seg = t & 3;
  const float* src = in + ((size_t)e * R + r0 + row) * C + c0 + seg * 16;
#pragma unroll
  for (int i = 0; i < 4; ++i) {
    float4 v = *(const float4*)(src + i * 4);
    tile[row][seg * 16 + i * 4 + 0] = v.x;
    tile[row][seg * 16 + i * 4 + 1] = v.y;
    tile[row][seg * 16 + i * 4 + 2] = v.z;
    tile[row][seg * 16 + i * 4 + 3] = v.w;
  }
  __syncthreads();
  int c = t >> 2;
  ushort vals[16];
#pragma unroll
  for (int j = 0; j < 16; ++j) vals[j] = f2bf(tile[seg * 16 + j][c]);
  ushort* dst = out + ((size_t)e * C + c0 + c) * R + r0 + seg * 16;
  *(uint4*)(dst)     = *(uint4*)&vals[0];
  *(uint4*)(dst + 8) = *(uint4*)&vals[8];
}

// ---------------- GEMM1: hdn[slot, n] = gelu( Xg @ w1 + b1 )  (128x128 tile, BK=64)
// A rows gathered from xb via slot list (per-lane global addr); B from w1t (E,DFF,H).
// LDS XOR-swizzled via pre-swizzled global source (rule #21): content(row,slot)=global(row,slot^(row&7)).
__global__ __launch_bounds__(256, 2) void gemm1_kernel(
    const ushort* __restrict__ xb, const ushort* __restrict__ w1t,
    const float* __restrict__ b1, const int* __restrict__ counts,
    const int* __restrict__ lslot, ushort* __restrict__ hdn, int c0, int DC) {
  int e = blockIdx.z;
  int cnt = counts[e];
  int m0 = blockIdx.y * 128;
  if (m0 >= cnt) return;
  int n0 = c0 + blockIdx.x * 128;   // global DFF column base

  __shared__ ushort sA[128 * 64];
  __shared__ ushort sB[128 * 64];
  int tid = threadIdx.x, lane = tid & 63, wid = tid >> 6;
  int wm = wid >> 1, wn = wid & 1;
  const int* lst = lslot + e * T_;
  const ushort* w1e = w1t + (size_t)e * DFF_ * H_;

  int lrow = lane >> 3;                 // row within an 8-row staging group
  int scol = ((lane & 7) ^ lrow) * 8;   // pre-swizzled source column (elements)

  const ushort* asrc[4]; const ushort* bsrc[4];
#pragma unroll
  for (int is = 0; is < 4; ++is) {
    int row = (wid * 4 + is) * 8 + lrow;
    int r = m0 + row; if (r > cnt - 1) r = cnt - 1;
    asrc[is] = xb + (size_t)(lst[r] >> 1) * H_ + scol;
    bsrc[is] = w1e + (size_t)(n0 + row) * H_ + scol;
  }

  f32x4 acc[4][4];
#pragma unroll
  for (int i = 0; i < 4; ++i)
#pragma unroll
    for (int j = 0; j < 4; ++j) acc[i][j] = (f32x4){0.f, 0.f, 0.f, 0.f};

  for (int k0 = 0; k0 < H_; k0 += 64) {
    __syncthreads();
#pragma unroll
    for (int is = 0; is < 4; ++is) {
      gload16(asrc[is] + k0, &sA[(wid * 4 + is) * 512]);
      gload16(bsrc[is] + k0, &sB[(wid * 4 + is) * 512]);
    }
    __syncthreads();
#pragma unroll
    for (int s = 0; s < 2; ++s) {
      bf16x8 af[4], bfr[4];
#pragma unroll
      for (int i = 0; i < 4; ++i) {
        int row = wm * 64 + i * 16 + (lane & 15);
        af[i] = *(const bf16x8*)(&sA[row * 64 + (((s * 4 + (lane >> 4)) ^ (row & 7)) * 8)]);
      }
#pragma unroll
      for (int i = 0; i < 4; ++i) {
        int row = wn * 64 + i * 16 + (lane & 15);
        bfr[i] = *(const bf16x8*)(&sB[row * 64 + (((s * 4 + (lane >> 4)) ^ (row & 7)) * 8)]);
      }
#pragma unroll
      for (int i = 0; i < 4; ++i)
#pragma unroll
        for (int j = 0; j < 4; ++j)
          acc[i][j] = __builtin_amdgcn_mfma_f32_16x16x32_bf16(af[i], bfr[j], acc[i][j], 0, 0, 0);
    }
  }

  // epilogue: bias + tanh-gelu -> bf16 -> hdn[slot][col-c0]
  int cl = lane & 15, rg = lane >> 4;
  float b1v[4];
#pragma unroll
  for (int j = 0; j < 4; ++j) b1v[j] = b1[e * DFF_ + n0 + wn * 64 + j * 16 + cl];
#pragma unroll
  for (int i = 0; i < 4; ++i) {
    int rbase = m0 + wm * 64 + i * 16 + rg * 4;
#pragma unroll
    for (int r = 0; r < 4; ++r) {
      int gr = rbase + r;
      if (gr < cnt) {
        ushort* hrow = hdn + (size_t)lst[gr] * DC + (n0 - c0) + wn * 64 + cl;
#pragma unroll
        for (int j = 0; j < 4; ++j) {
          float v = acc[i][j][r] + b1v[j];
          float t = v + 0.044715f * v * v * v;
          float exv = __expf(1.5957691216057308f * t);   // e^{2*0.7978845608*t}
          float th = 1.0f - 2.0f / (exv + 1.0f);
          hrow[j * 16] = f2bf(0.5f * v * (1.0f + th));
        }
      }
    }
  }
}

// ---------------- GEMM2: O2[slot, :] (+)= hdn[slot, :] @ w2   (128x128 tile, BK=64)
__global__ __launch_bounds__(256, 2) void gemm2_kernel(
    const ushort* __restrict__ hdn, const ushort* __restrict__ w2t,
    const int* __restrict__ counts, const int* __restrict__ lslot,
    float* __restrict__ O2, int c0, int DC, int first) {
  int e = blockIdx.z;
  int cnt = counts[e];
  int m0 = blockIdx.y * 128;
  if (m0 >= cnt) return;
  int n0 = blockIdx.x * 128;   // H column base

  __shared__ ushort sA[128 * 64];
  __shared__ ushort sB[128 * 64];
  int tid = threadIdx.x, lane = tid & 63, wid = tid >> 6;
  int wm = wid >> 1, wn = wid & 1;
  const int* lst = lslot + e * T_;
  const ushort* w2e = w2t + (size_t)e * H_ * DFF_ + c0;

  int lrow = lane >> 3;
  int scol = ((lane & 7) ^ lrow) * 8;

  const ushort* asrc[4]; const ushort* bsrc[4];
#pragma unroll
  for (int is = 0; is < 4; ++is) {
    int row = (wid * 4 + is) * 8 + lrow;
    int r = m0 + row; if (r > cnt - 1) r = cnt - 1;
    asrc[is] = hdn + (size_t)lst[r] * DC + scol;
    bsrc[is] = w2e + (size_t)(n0 + row) * DFF_ + scol;
  }

  f32x4 acc[4][4];
#pragma unroll
  for (int i = 0; i < 4; ++i)
#pragma unroll
    for (int j = 0; j < 4; ++j) acc[i][j] = (f32x4){0.f, 0.f, 0.f, 0.f};

  for (int k0 = 0; k0 < DC; k0 += 64) {
    __syncthreads();
#pragma unroll
    for (int is = 0; is < 4; ++is) {
      gload16(asrc[is] + k0, &sA[(wid * 4 + is) * 512]);
      gload16(bsrc[is] + k0, &sB[(wid * 4 + is) * 512]);
    }
    __syncthreads();
#pragma unroll
    for (int s = 0; s < 2; ++s) {
      bf16x8 af[4], bfr[4];
#pragma unroll
      for (int i = 0; i < 4; ++i) {
        int row = wm * 64 + i * 16 + (lane & 15);
        af[i] = *(const bf16x8*)(&sA[row * 64 + (((s * 4 + (lane >> 4)) ^ (row & 7)) * 8)]);
      }
#pragma unroll
      for (int i = 0; i < 4; ++i) {
        int row = wn * 64 + i * 16 + (lane & 15);
        bfr[i] = *(const bf16x8*)(&sB[row * 64 + (((s * 4 + (lane >> 4)) ^ (row & 7)) * 8)]);
      }
#pragma unroll
      for (int i = 0; i < 4; ++i)
#pragma unroll
        for (int j = 0; j < 4; ++j)
          acc[i][j] = __builtin_amdgcn_mfma_f32_16x16x32_bf16(af[i], bfr[j], acc[i][j], 0, 0, 0);
    }
  }

  int cl = lane & 15, rg = lane >> 4;
#pragma unroll
  for (int i = 0; i < 4; ++i) {
    int rbase = m0 + wm * 64 + i * 16 + rg * 4;
#pragma unroll
    for (int r = 0; r < 4; ++r) {
      int gr = rbase + r;
      if (gr < cnt) {
        float* orow = O2 + (size_t)lst[gr] * H_ + n0 + wn * 64 + cl;
        if (first) {
#pragma unroll
          for (int j = 0; j < 4; ++j) orow[j * 16] = acc[i][j][r];
        } else {
#pragma unroll
          for (int j = 0; j < 4; ++j) orow[j * 16] += acc[i][j][r];
        }
      }
    }
  }
}

// ---------------- combine: out[t] = sum_k slotw[2t+k] * (O2[2t+k] + b2[slote[2t+k]])
__global__ void combine_kernel(const float* __restrict__ O2, const float* __restrict__ b2,
                               const float* __restrict__ slotw, const int* __restrict__ slote,
                               float* __restrict__ out) {
  int idx = blockIdx.x * 256 + threadIdx.x;   // one float4 per thread
  int t = idx >> 7;                            // H_/4 = 128 float4 per row
  int h4 = (idx & 127) * 4;
  int s0 = 2 * t, s1 = 2 * t + 1;
  float w0 = slotw[s0], w1 = slotw[s1];
  int e0 = slote[s0], e1 = slote[s1];
  float4 a = *(const float4*)(O2 + (size_t)s0 * H_ + h4);
  float4 b = *(const float4*)(O2 + (size_t)s1 * H_ + h4);
  float4 c = *(const float4*)(b2 + e0 * H_ + h4);
  float4 d = *(const float4*)(b2 + e1 * H_ + h4);
  float4 o;
  o.x = w0 * (a.x + c.x) + w1 * (b.x + d.x);
  o.y = w0 * (a.y + c.y) + w1 * (b.y + d.y);
  o.z = w0 * (a.z + c.z) + w1 * (b.z + d.z);
  o.w = w0 * (a.w + c.w) + w1 * (b.w + d.w);
  *(float4*)(out + (size_t)t * H_ + h4) = o;
}

extern "C" void kernel_launch(void* const* d_in, const int* in_sizes, int n_in,
                              void* d_out, int out_size, void* d_ws, size_t ws_size,
                              hipStream_t stream) {
  const float* x  = (const float*)d_in[0];
  const float* gw = (const float*)d_in[1];
  const float* w1 = (const float*)d_in[2];
  const float* b1 = (const float*)d_in[3];
  const float* w2 = (const float*)d_in[4];
  const float* b2 = (const float*)d_in[5];
  float* out = (float*)d_out;

  char* ws = (char*)d_ws;
  size_t off = 0;
  auto alloc = [&](size_t bytes) -> void* {
    void* p = ws + off; off += (bytes + 255) & ~(size_t)255; return p;
  };
  int*    counts = (int*)alloc(256);
  int*    lslot  = (int*)alloc((size_t)E_ * T_ * 4);
  float*  slotw  = (float*)alloc((size_t)NSLOT * 4);
  int*    slote  = (int*)alloc((size_t)NSLOT * 4);
  ushort* w1t    = (ushort*)alloc((size_t)E_ * DFF_ * H_ * 2);
  ushort* w2t    = (ushort*)alloc((size_t)E_ * H_ * DFF_ * 2);
  ushort* xb     = (ushort*)alloc((size_t)T_ * H_ * 2);
  float*  O2     = (float*)alloc((size_t)NSLOT * H_ * 4);

  int NC = 1;   // DFF chunking factor, only >1 if ws is tight
  while (NC < 16 && off + (size_t)NSLOT * (DFF_ / NC) * 2 > ws_size) NC *= 2;
  int DC = DFF_ / NC;
  ushort* hdn = (ushort*)alloc((size_t)NSLOT * DC * 2);

  hipMemsetAsync(counts, 0, 256, stream);
  cast_x_kernel<<<T_ * H_ / (256 * 8), 256, 0, stream>>>(x, xb);
  router_kernel<<<T_ / 4, 256, 0, stream>>>(x, gw, counts, lslot, slotw, slote);
  transpose_cast_kernel<<<dim3(DFF_ / 64, H_ / 64, E_), 256, 0, stream>>>(w1, w1t, H_, DFF_);
  transpose_cast_kernel<<<dim3(H_ / 64, DFF_ / 64, E_), 256, 0, stream>>>(w2, w2t, DFF_, H_);

  for (int c = 0; c < NC; ++c) {
    gemm1_kernel<<<dim3(DC / 128, T_ / 128, E_), 256, 0, stream>>>(
        xb, w1t, b1, counts, lslot, hdn, c * DC, DC);
    gemm2_kernel<<<dim3(H_ / 128, T_ / 128, E_), 256, 0, stream>>>(
        hdn, w2t, counts, lslot, O2, c * DC, DC, c == 0);
  }
  combine_kernel<<<T_ * H_ / 1024, 256, 0, stream>>>(O2, b2, slotw, slote, out);
}

// Round 4
// 180.668 us; speedup vs baseline: 4.4092x; 2.0081x over previous
//
#include <hip/hip_runtime.h>
#include <hip/hip_bf16.h>

#define E_    8
#define H_    512
#define DFF_  2048
#define T_    8192
#define NSLOT (2 * T_)

typedef float  f32x4  __attribute__((ext_vector_type(4)));
typedef short  bf16x8 __attribute__((ext_vector_type(8)));

static __device__ __forceinline__ ushort f2bf(float f) {
  union { float f; unsigned u; } v; v.f = f;
  unsigned r = v.u + 0x7FFFu + ((v.u >> 16) & 1u);
  return (ushort)(r >> 16);
}

// async global->LDS, 16B per lane; LDS dest is wave-uniform base + lane*16
static __device__ __forceinline__ void gload16(const void* g, void* l) {
  __builtin_amdgcn_global_load_lds((const __attribute__((address_space(1))) void*)g,
                                   (__attribute__((address_space(3))) void*)l, 16, 0, 0);
}

// ---------------- R1: fused x-cast + router (no atomics)
__global__ void route_cast_kernel(const float* __restrict__ x, const float* __restrict__ gw,
                                  ushort* __restrict__ xb,
                                  float* __restrict__ slotw, int* __restrict__ slote) {
  int tokn = (blockIdx.x * blockDim.x + threadIdx.x) >> 6;
  int lane = threadIdx.x & 63;
  if (tokn >= T_) return;
  const float4* xr = (const float4*)(x + (size_t)tokn * H_ + lane * 8);
  float4 x0 = xr[0], x1 = xr[1];
  ushort v[8] = {f2bf(x0.x), f2bf(x0.y), f2bf(x0.z), f2bf(x0.w),
                 f2bf(x1.x), f2bf(x1.y), f2bf(x1.z), f2bf(x1.w)};
  *(uint4*)(xb + (size_t)tokn * H_ + lane * 8) = *(uint4*)v;

  float acc[E_];
#pragma unroll
  for (int e = 0; e < E_; ++e) {
    const float4* gr = (const float4*)(gw + e * H_ + lane * 8);
    float4 g0 = gr[0], g1 = gr[1];
    acc[e] = x0.x*g0.x + x0.y*g0.y + x0.z*g0.z + x0.w*g0.w
           + x1.x*g1.x + x1.y*g1.y + x1.z*g1.z + x1.w*g1.w;
  }
#pragma unroll
  for (int e = 0; e < E_; ++e) {
#pragma unroll
    for (int off = 32; off; off >>= 1)
      acc[e] += __shfl_xor(acc[e], off);
  }
  if (lane == 0) {
    float v1 = -1e30f, v2 = -1e30f; int i1 = 0, i2 = 0;
#pragma unroll
    for (int e = 0; e < E_; ++e) {
      float vv = acc[e];
      if (vv > v1)      { v2 = v1; i2 = i1; v1 = vv; i1 = e; }
      else if (vv > v2) { v2 = vv; i2 = e; }
    }
    float ex = expf(v2 - v1);
    float inv = 1.0f / (1.0f + ex);
    slote[2 * tokn] = i1;     slotw[2 * tokn] = inv;
    slote[2 * tokn + 1] = i2; slotw[2 * tokn + 1] = ex * inv;
  }
}

// ---------------- R2: deterministic stable counting sort of 16384 slots into
// per-expert lists (layout lslot[e*T_ + local]). Single 1024-thread block, no atomics.
__global__ __launch_bounds__(1024) void listbuild_kernel(
    const int* __restrict__ slote, int* __restrict__ counts, int* __restrict__ lslot) {
  int tid = threadIdx.x, lane = tid & 63, wv = tid >> 6;   // 16 waves
  int base = tid * 16;
  int myexp[16];
  unsigned char cnt[E_] = {0, 0, 0, 0, 0, 0, 0, 0};
#pragma unroll
  for (int i = 0; i < 16; ++i) {
    int e = slote[base + i];
    myexp[i] = e;
    cnt[e]++;
  }
  // pack counts: lo = experts 0..3 (16b lanes), hi = experts 4..7
  unsigned long long lo = 0, hi = 0;
#pragma unroll
  for (int e = 0; e < 4; ++e) {
    lo |= (unsigned long long)cnt[e] << (16 * e);
    hi |= (unsigned long long)cnt[e + 4] << (16 * e);
  }
  unsigned long long mylo = lo, myhi = hi;
  // wave inclusive scan
#pragma unroll
  for (int off = 1; off < 64; off <<= 1) {
    unsigned long long tl = __shfl_up(lo, off);
    unsigned long long th = __shfl_up(hi, off);
    if (lane >= off) { lo += tl; hi += th; }
  }
  __shared__ unsigned long long wtotlo[16], wtothi[16];
  __shared__ unsigned long long wbaselo[16], wbasehi[16];
  if (lane == 63) { wtotlo[wv] = lo; wtothi[wv] = hi; }
  __syncthreads();
  if (tid == 0) {
    unsigned long long rl = 0, rh = 0;
#pragma unroll
    for (int w2 = 0; w2 < 16; ++w2) {
      wbaselo[w2] = rl; wbasehi[w2] = rh;
      rl += wtotlo[w2]; rh += wtothi[w2];
    }
#pragma unroll
    for (int e = 0; e < 4; ++e) {
      counts[e]     = (int)((rl >> (16 * e)) & 0xFFFF);
      counts[e + 4] = (int)((rh >> (16 * e)) & 0xFFFF);
    }
  }
  __syncthreads();
  // expert-LOCAL exclusive prefix for this thread (bug fix: no global ebase here)
  unsigned long long exlo = wbaselo[wv] + lo - mylo;
  unsigned long long exhi = wbasehi[wv] + hi - myhi;
  int pos[E_];
#pragma unroll
  for (int e = 0; e < 4; ++e) {
    pos[e]     = (int)((exlo >> (16 * e)) & 0xFFFF);
    pos[e + 4] = (int)((exhi >> (16 * e)) & 0xFFFF);
  }
#pragma unroll
  for (int i = 0; i < 16; ++i) {
    int e = myexp[i];
    lslot[e * T_ + pos[e]] = base + i;
    pos[e]++;
  }
}

// ---------------- transpose + fp32->bf16 cast: in (E,R,C) f32 -> out (E,C,R) bf16
__global__ void transpose_cast_kernel(const float* __restrict__ in,
                                      ushort* __restrict__ out, int R, int C) {
  int e = blockIdx.z, r0 = blockIdx.y * 64, c0 = blockIdx.x * 64;
  __shared__ float tile[64][65];
  int t = threadIdx.x;
  int row = t >> 2, seg = t & 3;
  const float* src = in + ((size_t)e * R + r0 + row) * C + c0 + seg * 16;
#pragma unroll
  for (int i = 0; i < 4; ++i) {
    float4 v = *(const float4*)(src + i * 4);
    tile[row][seg * 16 + i * 4 + 0] = v.x;
    tile[row][seg * 16 + i * 4 + 1] = v.y;
    tile[row][seg * 16 + i * 4 + 2] = v.z;
    tile[row][seg * 16 + i * 4 + 3] = v.w;
  }
  __syncthreads();
  int c = t >> 2;
  ushort vals[16];
#pragma unroll
  for (int j = 0; j < 16; ++j) vals[j] = f2bf(tile[seg * 16 + j][c]);
  ushort* dst = out + ((size_t)e * C + c0 + c) * R + r0 + seg * 16;
  *(uint4*)(dst)     = *(uint4*)&vals[0];
  *(uint4*)(dst + 8) = *(uint4*)&vals[8];
}

// ---------------- GEMM1: hdn[slot, n] = gelu( Xg @ w1 + b1 )  (128x128 tile, BK=64)
__global__ __launch_bounds__(256, 2) void gemm1_kernel(
    const ushort* __restrict__ xb, const ushort* __restrict__ w1t,
    const float* __restrict__ b1, const int* __restrict__ counts,
    const int* __restrict__ lslot, ushort* __restrict__ hdn, int c0, int DC) {
  int e = blockIdx.z;
  int cnt = counts[e];
  int m0 = blockIdx.y * 128;
  if (m0 >= cnt) return;
  int n0 = c0 + blockIdx.x * 128;   // global DFF column base

  __shared__ ushort sA[128 * 64];
  __shared__ ushort sB[128 * 64];
  int tid = threadIdx.x, lane = tid & 63, wid = tid >> 6;
  int wm = wid >> 1, wn = wid & 1;
  const int* lst = lslot + e * T_;
  const ushort* w1e = w1t + (size_t)e * DFF_ * H_;

  int lrow = lane >> 3;                 // row within an 8-row staging group
  int scol = ((lane & 7) ^ lrow) * 8;   // pre-swizzled source column (elements)

  const ushort* asrc[4]; const ushort* bsrc[4];
#pragma unroll
  for (int is = 0; is < 4; ++is) {
    int row = (wid * 4 + is) * 8 + lrow;
    int r = m0 + row; if (r > cnt - 1) r = cnt - 1;
    asrc[is] = xb + (size_t)(lst[r] >> 1) * H_ + scol;
    bsrc[is] = w1e + (size_t)(n0 + row) * H_ + scol;
  }

  f32x4 acc[4][4];
#pragma unroll
  for (int i = 0; i < 4; ++i)
#pragma unroll
    for (int j = 0; j < 4; ++j) acc[i][j] = (f32x4){0.f, 0.f, 0.f, 0.f};

  for (int k0 = 0; k0 < H_; k0 += 64) {
    __syncthreads();
#pragma unroll
    for (int is = 0; is < 4; ++is) {
      gload16(asrc[is] + k0, &sA[(wid * 4 + is) * 512]);
      gload16(bsrc[is] + k0, &sB[(wid * 4 + is) * 512]);
    }
    __syncthreads();
#pragma unroll
    for (int s = 0; s < 2; ++s) {
      bf16x8 af[4], bfr[4];
#pragma unroll
      for (int i = 0; i < 4; ++i) {
        int row = wm * 64 + i * 16 + (lane & 15);
        af[i] = *(const bf16x8*)(&sA[row * 64 + (((s * 4 + (lane >> 4)) ^ (row & 7)) * 8)]);
      }
#pragma unroll
      for (int i = 0; i < 4; ++i) {
        int row = wn * 64 + i * 16 + (lane & 15);
        bfr[i] = *(const bf16x8*)(&sB[row * 64 + (((s * 4 + (lane >> 4)) ^ (row & 7)) * 8)]);
      }
#pragma unroll
      for (int i = 0; i < 4; ++i)
#pragma unroll
        for (int j = 0; j < 4; ++j)
          acc[i][j] = __builtin_amdgcn_mfma_f32_16x16x32_bf16(af[i], bfr[j], acc[i][j], 0, 0, 0);
    }
  }

  // epilogue: bias + tanh-gelu -> bf16 -> hdn[slot][col-c0]
  int cl = lane & 15, rg = lane >> 4;
  float b1v[4];
#pragma unroll
  for (int j = 0; j < 4; ++j) b1v[j] = b1[e * DFF_ + n0 + wn * 64 + j * 16 + cl];
#pragma unroll
  for (int i = 0; i < 4; ++i) {
    int rbase = m0 + wm * 64 + i * 16 + rg * 4;
#pragma unroll
    for (int r = 0; r < 4; ++r) {
      int gr = rbase + r;
      if (gr < cnt) {
        ushort* hrow = hdn + (size_t)lst[gr] * DC + (n0 - c0) + wn * 64 + cl;
#pragma unroll
        for (int j = 0; j < 4; ++j) {
          float v = acc[i][j][r] + b1v[j];
          float t = v + 0.044715f * v * v * v;
          float exv = __expf(1.5957691216057308f * t);   // e^{2*0.7978845608*t}
          float th = 1.0f - 2.0f / (exv + 1.0f);
          hrow[j * 16] = f2bf(0.5f * v * (1.0f + th));
        }
      }
    }
  }
}

// ---------------- GEMM2: O2[slot, :] (+)= hdn[slot, :] @ w2   (128x128 tile, BK=64)
__global__ __launch_bounds__(256, 2) void gemm2_kernel(
    const ushort* __restrict__ hdn, const ushort* __restrict__ w2t,
    const int* __restrict__ counts, const int* __restrict__ lslot,
    float* __restrict__ O2, int c0, int DC, int first) {
  int e = blockIdx.z;
  int cnt = counts[e];
  int m0 = blockIdx.y * 128;
  if (m0 >= cnt) return;
  int n0 = blockIdx.x * 128;   // H column base

  __shared__ ushort sA[128 * 64];
  __shared__ ushort sB[128 * 64];
  int tid = threadIdx.x, lane = tid & 63, wid = tid >> 6;
  int wm = wid >> 1, wn = wid & 1;
  const int* lst = lslot + e * T_;
  const ushort* w2e = w2t + (size_t)e * H_ * DFF_ + c0;

  int lrow = lane >> 3;
  int scol = ((lane & 7) ^ lrow) * 8;

  const ushort* asrc[4]; const ushort* bsrc[4];
#pragma unroll
  for (int is = 0; is < 4; ++is) {
    int row = (wid * 4 + is) * 8 + lrow;
    int r = m0 + row; if (r > cnt - 1) r = cnt - 1;
    asrc[is] = hdn + (size_t)lst[r] * DC + scol;
    bsrc[is] = w2e + (size_t)(n0 + row) * DFF_ + scol;
  }

  f32x4 acc[4][4];
#pragma unroll
  for (int i = 0; i < 4; ++i)
#pragma unroll
    for (int j = 0; j < 4; ++j) acc[i][j] = (f32x4){0.f, 0.f, 0.f, 0.f};

  for (int k0 = 0; k0 < DC; k0 += 64) {
    __syncthreads();
#pragma unroll
    for (int is = 0; is < 4; ++is) {
      gload16(asrc[is] + k0, &sA[(wid * 4 + is) * 512]);
      gload16(bsrc[is] + k0, &sB[(wid * 4 + is) * 512]);
    }
    __syncthreads();
#pragma unroll
    for (int s = 0; s < 2; ++s) {
      bf16x8 af[4], bfr[4];
#pragma unroll
      for (int i = 0; i < 4; ++i) {
        int row = wm * 64 + i * 16 + (lane & 15);
        af[i] = *(const bf16x8*)(&sA[row * 64 + (((s * 4 + (lane >> 4)) ^ (row & 7)) * 8)]);
      }
#pragma unroll
      for (int i = 0; i < 4; ++i) {
        int row = wn * 64 + i * 16 + (lane & 15);
        bfr[i] = *(const bf16x8*)(&sB[row * 64 + (((s * 4 + (lane >> 4)) ^ (row & 7)) * 8)]);
      }
#pragma unroll
      for (int i = 0; i < 4; ++i)
#pragma unroll
        for (int j = 0; j < 4; ++j)
          acc[i][j] = __builtin_amdgcn_mfma_f32_16x16x32_bf16(af[i], bfr[j], acc[i][j], 0, 0, 0);
    }
  }

  int cl = lane & 15, rg = lane >> 4;
#pragma unroll
  for (int i = 0; i < 4; ++i) {
    int rbase = m0 + wm * 64 + i * 16 + rg * 4;
#pragma unroll
    for (int r = 0; r < 4; ++r) {
      int gr = rbase + r;
      if (gr < cnt) {
        float* orow = O2 + (size_t)lst[gr] * H_ + n0 + wn * 64 + cl;
        if (first) {
#pragma unroll
          for (int j = 0; j < 4; ++j) orow[j * 16] = acc[i][j][r];
        } else {
#pragma unroll
          for (int j = 0; j < 4; ++j) orow[j * 16] += acc[i][j][r];
        }
      }
    }
  }
}

// ---------------- combine: out[t] = sum_k slotw[2t+k] * (O2[2t+k] + b2[slote[2t+k]])
__global__ void combine_kernel(const float* __restrict__ O2, const float* __restrict__ b2,
                               const float* __restrict__ slotw, const int* __restrict__ slote,
                               float* __restrict__ out) {
  int idx = blockIdx.x * 256 + threadIdx.x;   // one float4 per thread
  int t = idx >> 7;                            // H_/4 = 128 float4 per row
  int h4 = (idx & 127) * 4;
  int s0 = 2 * t, s1 = 2 * t + 1;
  float w0 = slotw[s0], w1 = slotw[s1];
  int e0 = slote[s0], e1 = slote[s1];
  float4 a = *(const float4*)(O2 + (size_t)s0 * H_ + h4);
  float4 b = *(const float4*)(O2 + (size_t)s1 * H_ + h4);
  float4 c = *(const float4*)(b2 + e0 * H_ + h4);
  float4 d = *(const float4*)(b2 + e1 * H_ + h4);
  float4 o;
  o.x = w0 * (a.x + c.x) + w1 * (b.x + d.x);
  o.y = w0 * (a.y + c.y) + w1 * (b.y + d.y);
  o.z = w0 * (a.z + c.z) + w1 * (b.z + d.z);
  o.w = w0 * (a.w + c.w) + w1 * (b.w + d.w);
  *(float4*)(out + (size_t)t * H_ + h4) = o;
}

extern "C" void kernel_launch(void* const* d_in, const int* in_sizes, int n_in,
                              void* d_out, int out_size, void* d_ws, size_t ws_size,
                              hipStream_t stream) {
  const float* x  = (const float*)d_in[0];
  const float* gw = (const float*)d_in[1];
  const float* w1 = (const float*)d_in[2];
  const float* b1 = (const float*)d_in[3];
  const float* w2 = (const float*)d_in[4];
  const float* b2 = (const float*)d_in[5];
  float* out = (float*)d_out;

  char* ws = (char*)d_ws;
  size_t off = 0;
  auto alloc = [&](size_t bytes) -> void* {
    void* p = ws + off; off += (bytes + 255) & ~(size_t)255; return p;
  };
  int*    counts = (int*)alloc(256);
  int*    lslot  = (int*)alloc((size_t)E_ * T_ * 4);
  float*  slotw  = (float*)alloc((size_t)NSLOT * 4);
  int*    slote  = (int*)alloc((size_t)NSLOT * 4);
  ushort* w1t    = (ushort*)alloc((size_t)E_ * DFF_ * H_ * 2);
  ushort* w2t    = (ushort*)alloc((size_t)E_ * H_ * DFF_ * 2);
  ushort* xb     = (ushort*)alloc((size_t)T_ * H_ * 2);
  float*  O2     = (float*)alloc((size_t)NSLOT * H_ * 4);

  int NC = 1;   // DFF chunking factor, only >1 if ws is tight
  while (NC < 16 && off + (size_t)NSLOT * (DFF_ / NC) * 2 > ws_size) NC *= 2;
  int DC = DFF_ / NC;
  ushort* hdn = (ushort*)alloc((size_t)NSLOT * DC * 2);

  route_cast_kernel<<<T_ / 4, 256, 0, stream>>>(x, gw, xb, slotw, slote);
  listbuild_kernel<<<1, 1024, 0, stream>>>(slote, counts, lslot);
  transpose_cast_kernel<<<dim3(DFF_ / 64, H_ / 64, E_), 256, 0, stream>>>(w1, w1t, H_, DFF_);
  transpose_cast_kernel<<<dim3(H_ / 64, DFF_ / 64, E_), 256, 0, stream>>>(w2, w2t, DFF_, H_);

  for (int c = 0; c < NC; ++c) {
    gemm1_kernel<<<dim3(DC / 128, T_ / 128, E_), 256, 0, stream>>>(
        xb, w1t, b1, counts, lslot, hdn, c * DC, DC);
    gemm2_kernel<<<dim3(H_ / 128, T_ / 128, E_), 256, 0, stream>>>(
        hdn, w2t, counts, lslot, O2, c * DC, DC, c == 0);
  }
  combine_kernel<<<T_ * H_ / 1024, 256, 0, stream>>>(O2, b2, slotw, slote, out);
}